// Round 10
// baseline (124.580 us; speedup 1.0000x reference)
//
#include <hip/hip_runtime.h>
#include <hip/hip_bf16.h>

#define LSEQ   1024
#define NHEAD  8
#define DH     64
#define DIM    512
#define CHUNK  64
#define NCHUNK 16
#define NHTOT  16
#define LDB    68    // ushort LDS row stride for proj
#define LDA    72    // ushort LDS row stride for attn/chunksum (144 B, 16B-aligned)

typedef __attribute__((ext_vector_type(8))) short short8;
typedef __attribute__((ext_vector_type(4))) float floatx4;

__device__ __forceinline__ float softplusf_(float x) {
    if (x > 20.f) return x;
    return log1pf(expf(x));
}
__device__ __forceinline__ unsigned short bf16_rne(float x) {
    unsigned int u = __float_as_uint(x);
    u += 0x7FFFu + ((u >> 16) & 1u);
    return (unsigned short)(u >> 16);
}
__device__ __forceinline__ float bf16_tof(unsigned short h) {
    return __uint_as_float(((unsigned int)h) << 16);
}

// ---------------------------------------------------------------------------
// Kernel A: C = X @ W^T, single-pass bf16 MFMA.  64x64 tile, grid (32,8,3).
// ---------------------------------------------------------------------------
__global__ __launch_bounds__(256) void proj_kernel(
    const float* __restrict__ query, const float* __restrict__ key,
    const float* __restrict__ Wq, const float* __restrict__ Wk,
    const float* __restrict__ Wv,
    unsigned short* __restrict__ qbuf, unsigned short* __restrict__ kbuf,
    unsigned short* __restrict__ vbuf)
{
    const int mt  = blockIdx.x;
    const int ot  = blockIdx.y;
    const int sel = blockIdx.z;
    const int t   = threadIdx.x;

    const float* __restrict__ X = (sel == 0) ? query : key;
    const float* __restrict__ W = (sel == 0) ? Wq : (sel == 1) ? Wk : Wv;
    unsigned short* __restrict__ obuf = (sel == 0) ? qbuf : (sel == 1) ? kbuf : vbuf;

    __shared__ unsigned short As[64 * LDB];
    __shared__ unsigned short Bs[64 * LDB];

    const int m0 = mt * 64, o0 = ot * 64;
    const int lane = t & 63, wave = t >> 6;
    const int quad = lane >> 4, l16 = lane & 15;
    const int wm = wave >> 1, wn = wave & 1;

    const int srow = t >> 2;
    const int sc16 = (t & 3) * 16;

    floatx4 acc[2][2];
    #pragma unroll
    for (int i = 0; i < 2; ++i)
        #pragma unroll
        for (int j = 0; j < 2; ++j) acc[i][j] = (floatx4){0.f, 0.f, 0.f, 0.f};

    float4 ax[4], bx4[4];
    #pragma unroll
    for (int i = 0; i < 4; ++i) {
        ax[i]  = *(const float4*)&X[(size_t)(m0 + srow) * DIM + sc16 + i * 4];
        bx4[i] = *(const float4*)&W[(size_t)(o0 + srow) * DIM + sc16 + i * 4];
    }

    for (int kt = 0; kt < DIM; kt += 64) {
        __syncthreads();
        {
            short8 a0, a1, b0, b1;
            #pragma unroll
            for (int i = 0; i < 2; ++i) {
                const float va[4] = {ax[i].x, ax[i].y, ax[i].z, ax[i].w};
                const float vb[4] = {bx4[i].x, bx4[i].y, bx4[i].z, bx4[i].w};
                #pragma unroll
                for (int j = 0; j < 4; ++j) {
                    a0[i * 4 + j] = (short)bf16_rne(va[j]);
                    b0[i * 4 + j] = (short)bf16_rne(vb[j]);
                }
            }
            #pragma unroll
            for (int i = 2; i < 4; ++i) {
                const float va[4] = {ax[i].x, ax[i].y, ax[i].z, ax[i].w};
                const float vb[4] = {bx4[i].x, bx4[i].y, bx4[i].z, bx4[i].w};
                #pragma unroll
                for (int j = 0; j < 4; ++j) {
                    a1[(i - 2) * 4 + j] = (short)bf16_rne(va[j]);
                    b1[(i - 2) * 4 + j] = (short)bf16_rne(vb[j]);
                }
            }
            *(short8*)&As[srow * LDB + sc16]     = a0;
            *(short8*)&As[srow * LDB + sc16 + 8] = a1;
            *(short8*)&Bs[srow * LDB + sc16]     = b0;
            *(short8*)&Bs[srow * LDB + sc16 + 8] = b1;
        }
        __syncthreads();

        if (kt + 64 < DIM) {
            #pragma unroll
            for (int i = 0; i < 4; ++i) {
                ax[i]  = *(const float4*)&X[(size_t)(m0 + srow) * DIM + kt + 64 + sc16 + i * 4];
                bx4[i] = *(const float4*)&W[(size_t)(o0 + srow) * DIM + kt + 64 + sc16 + i * 4];
            }
        }

        #pragma unroll
        for (int s = 0; s < 2; ++s) {
            short8 af[2], bf[2];
            #pragma unroll
            for (int mi = 0; mi < 2; ++mi)
                af[mi] = *(const short8*)&As[(wm * 32 + mi * 16 + l16) * LDB + s * 32 + quad * 8];
            #pragma unroll
            for (int ni = 0; ni < 2; ++ni)
                bf[ni] = *(const short8*)&Bs[(wn * 32 + ni * 16 + l16) * LDB + s * 32 + quad * 8];
            #pragma unroll
            for (int ni = 0; ni < 2; ++ni)
                #pragma unroll
                for (int mi = 0; mi < 2; ++mi)
                    acc[mi][ni] = __builtin_amdgcn_mfma_f32_16x16x32_bf16(af[mi], bf[ni], acc[mi][ni], 0, 0, 0);
        }
    }

    const int h = ot;
    #pragma unroll
    for (int mi = 0; mi < 2; ++mi)
        #pragma unroll
        for (int ni = 0; ni < 2; ++ni) {
            const int d = wn * 32 + ni * 16 + l16;
            #pragma unroll
            for (int r = 0; r < 4; ++r) {
                const int m = m0 + wm * 32 + mi * 16 + quad * 4 + r;
                const int n = m >> 10, l = m & (LSEQ - 1);
                float val = acc[mi][ni][r];
                if (sel < 2) val = softplusf_(val);
                obuf[(((size_t)(n * NHEAD + h)) * LSEQ + l) * DH + d] = bf16_rne(val);
            }
        }
}

// ---------------------------------------------------------------------------
// Kernel B (MFMA): per-(c,nh,br) chunk sums, stored TRANSPOSED f32.
// Staging: thread = column (lane), wave = k-quarter -> coalesced 2B global
// reads, contiguous ushort4 LDS row writes (4-way conflict max; the old
// [(c4+j)*LDA+r] scalar scatter was ~16-way).
// ---------------------------------------------------------------------------
__global__ __launch_bounds__(256) void chunksum_kernel(
    const unsigned short* __restrict__ kbuf, const unsigned short* __restrict__ vbuf,
    const float* __restrict__ pw,
    float* __restrict__ Ssum, float* __restrict__ zsum)
{
    const int c  = blockIdx.x;
    const int nh = blockIdx.y;
    const int br = blockIdx.z;
    const int h  = nh & (NHEAD - 1);
    const int t  = threadIdx.x;
    const int lane = t & 63, wave = t >> 6;
    const int quad = lane >> 4, l16 = lane & 15;
    const int wm = wave >> 1, wn = wave & 1;

    __shared__ unsigned short kfT[64 * LDA];  // [d][k]
    __shared__ unsigned short vT[64 * LDA];   // [e][k]
    __shared__ float dpart[4][64];

    const size_t base = ((size_t)nh * LSEQ + (size_t)c * CHUNK) * DH;

    {
        const int col = t & 63;          // d / e
        const int kq  = (t >> 6) * 16;   // this wave's k-quarter
        const float w = pw[h * DH + col];
        unsigned short kfv[16], vvv[16];
        #pragma unroll
        for (int j = 0; j < 16; ++j) {
            const int k = kq + j;
            const unsigned short kraw = kbuf[base + (size_t)k * DH + col];
            vvv[j] = vbuf[base + (size_t)k * DH + col];
            if (br == 0) kfv[j] = kraw;
            else {
                const float pos = (float)(c * CHUNK + k);
                const float f = (br == 1) ? cosf(pos * w) : sinf(pos * w);
                kfv[j] = bf16_rne(bf16_tof(kraw) * f);
            }
        }
        #pragma unroll
        for (int g = 0; g < 4; ++g) {
            ushort4 a, b;
            a.x = kfv[g * 4]; a.y = kfv[g * 4 + 1]; a.z = kfv[g * 4 + 2]; a.w = kfv[g * 4 + 3];
            b.x = vvv[g * 4]; b.y = vvv[g * 4 + 1]; b.z = vvv[g * 4 + 2]; b.w = vvv[g * 4 + 3];
            *(ushort4*)&kfT[col * LDA + kq + g * 4] = a;
            *(ushort4*)&vT[col * LDA + kq + g * 4]  = b;
        }
    }
    __syncthreads();

    floatx4 acc[2][2];
    #pragma unroll
    for (int i = 0; i < 2; ++i)
        #pragma unroll
        for (int j = 0; j < 2; ++j) acc[i][j] = (floatx4){0.f, 0.f, 0.f, 0.f};

    #pragma unroll
    for (int kk = 0; kk < 2; ++kk) {
        short8 a[2], b[2];
        #pragma unroll
        for (int mi = 0; mi < 2; ++mi)
            a[mi] = *(const short8*)&vT[(wm * 32 + mi * 16 + l16) * LDA + kk * 32 + quad * 8];
        #pragma unroll
        for (int ni = 0; ni < 2; ++ni)
            b[ni] = *(const short8*)&kfT[(wn * 32 + ni * 16 + l16) * LDA + kk * 32 + quad * 8];
        #pragma unroll
        for (int ni = 0; ni < 2; ++ni)
            #pragma unroll
            for (int mi = 0; mi < 2; ++mi)
                acc[mi][ni] = __builtin_amdgcn_mfma_f32_16x16x32_bf16(a[mi], b[ni], acc[mi][ni], 0, 0, 0);
    }

    // z[d] = sum_k kfT[d][k]
    {
        const int d = t & 63, seg = t >> 6;
        float s = 0.f;
        #pragma unroll
        for (int j2 = 0; j2 < 2; ++j2) {
            const short8 v8 = *(const short8*)&kfT[d * LDA + seg * 16 + j2 * 8];
            #pragma unroll
            for (int j = 0; j < 8; ++j) s += bf16_tof((unsigned short)v8[j]);
        }
        dpart[seg][d] = s;
    }
    __syncthreads();
    if (t < DH) {
        zsum[((size_t)(br * NHTOT + nh) * NCHUNK + c) * DH + t] =
            dpart[0][t] + dpart[1][t] + dpart[2][t] + dpart[3][t];
    }

    float* Sg = Ssum + ((size_t)(br * NHTOT + nh) * NCHUNK + c) * (DH * DH);
    #pragma unroll
    for (int mi = 0; mi < 2; ++mi)
        #pragma unroll
        for (int ni = 0; ni < 2; ++ni) {
            const int d = wn * 32 + ni * 16 + l16;
            #pragma unroll
            for (int r = 0; r < 4; ++r) {
                const int e = wm * 32 + mi * 16 + quad * 4 + r;
                Sg[e * DH + d] = acc[mi][ni][r];
            }
        }
}

// ---------------------------------------------------------------------------
// Kernel B2: in-place exclusive prefix over chunks; grid (48, 16) = 768 blocks.
// (R8 measured: inlining this into attn serially cost +8 us — keep parallel.)
// ---------------------------------------------------------------------------
__global__ __launch_bounds__(256) void scan_kernel(
    float* __restrict__ Ssum, float* __restrict__ zsum)
{
    const int b = blockIdx.x;
    const int s = blockIdx.y;
    const int idx = s * 256 + threadIdx.x;

    float* S = Ssum + (size_t)b * NCHUNK * (DH * DH);
    float v[NCHUNK];
    #pragma unroll
    for (int c = 0; c < NCHUNK; ++c) v[c] = S[c * (DH * DH) + idx];
    float run = 0.f;
    #pragma unroll
    for (int c = 0; c < NCHUNK; ++c) {
        const float nv = v[c];
        S[c * (DH * DH) + idx] = run;
        run += nv;
    }
    if (s == 0 && threadIdx.x < DH) {
        float* z = zsum + (size_t)b * NCHUNK * DH;
        float zv[NCHUNK];
        #pragma unroll
        for (int c = 0; c < NCHUNK; ++c) zv[c] = z[c * DH + threadIdx.x];
        float zr = 0.f;
        #pragma unroll
        for (int c = 0; c < NCHUNK; ++c) {
            const float nv = zv[c];
            z[c * DH + threadIdx.x] = zr;
            zr += nv;
        }
    }
}

// ---------------------------------------------------------------------------
// Kernel C (MFMA): per-(c,nh,br) partial num/den; Ssum/zsum hold prefixes.
// numP written bf16 (den stays f32; out error +~0.2% rel, well under budget).
// ---------------------------------------------------------------------------
__global__ __launch_bounds__(256) void attn_kernel(
    const unsigned short* __restrict__ qbuf, const unsigned short* __restrict__ kbuf,
    const unsigned short* __restrict__ vbuf,
    const float* __restrict__ Ssum, const float* __restrict__ zsum,
    const float* __restrict__ pw, const float* __restrict__ pb,
    unsigned short* __restrict__ numP, float* __restrict__ denP)
{
    const int c  = blockIdx.x;
    const int nh = blockIdx.y;
    const int br = blockIdx.z;
    const int n  = nh >> 3;
    const int h  = nh & (NHEAD - 1);
    const int t  = threadIdx.x;
    const int lane = t & 63, wave = t >> 6;
    const int quad = lane >> 4, l16 = lane & 15;
    const int wm = wave >> 1, wn = wave & 1;

    __shared__ unsigned short qfL[64 * LDA];  // [l][d]
    __shared__ unsigned short kfL[64 * LDA];  // [k][d]
    __shared__ unsigned short vTL[64 * LDA];  // [e][k]
    __shared__ unsigned short SpL[64 * LDA];  // [e][d]  (S^T prefix)
    __shared__ unsigned short scA[64 * LDA];  // masked scores [l][k]
    __shared__ float zl[DH];
    __shared__ float dpart[8][64];

    const size_t base = ((size_t)nh * LSEQ + (size_t)c * CHUNK) * DH;
    const float* Sg = Ssum + ((size_t)(br * NHTOT + nh) * NCHUNK + c) * (DH * DH);
    const float PI_ = 3.14159265358979323846f;

    // v^T staging: thread = column e, wave = k-quarter (conflict-light)
    {
        const int col = t & 63;
        const int kq  = (t >> 6) * 16;
        unsigned short vvv[16];
        #pragma unroll
        for (int j = 0; j < 16; ++j)
            vvv[j] = vbuf[base + (size_t)(kq + j) * DH + col];
        #pragma unroll
        for (int g = 0; g < 4; ++g) {
            ushort4 b;
            b.x = vvv[g * 4]; b.y = vvv[g * 4 + 1]; b.z = vvv[g * 4 + 2]; b.w = vvv[g * 4 + 3];
            *(ushort4*)&vTL[col * LDA + kq + g * 4] = b;
        }
    }

    // q/k feature-mapped + S-prefix staging (row-major, b64 writes)
    #pragma unroll
    for (int i = 0; i < 4; ++i) {
        const int idx = i * 256 + t;
        const int r  = idx >> 4;
        const int c4 = (idx & 15) * 4;
        const ushort4 qv = *(const ushort4*)&qbuf[base + (size_t)r * DH + c4];
        const ushort4 kv = *(const ushort4*)&kbuf[base + (size_t)r * DH + c4];
        const float4  sv = *(const float4*)&Sg[r * DH + c4];
        const unsigned short* pq0 = (const unsigned short*)&qv;
        const unsigned short* pk0 = (const unsigned short*)&kv;
        ushort4 qh, kh, sh;
        unsigned short* pq = (unsigned short*)&qh;
        unsigned short* pk = (unsigned short*)&kh;
        unsigned short* ps = (unsigned short*)&sh;
        if (br == 0) {
            #pragma unroll
            for (int j = 0; j < 4; ++j) { pq[j] = pq0[j]; pk[j] = pk0[j]; }
        } else {
            const float4 wv  = *(const float4*)&pw[h * DH + c4];
            const float4 pbv = *(const float4*)&pb[h * DH + c4];
            const float w4[4] = {wv.x, wv.y, wv.z, wv.w};
            const float b4[4] = {pbv.x, pbv.y, pbv.z, pbv.w};
            const float pos = (float)(c * CHUNK + r);
            #pragma unroll
            for (int j = 0; j < 4; ++j) {
                const float bias = PI_ / (1.f + expf(-b4[j]));
                float tq, tk;
                if (br == 1) { tq = cosf(pos * w4[j] + bias); tk = cosf(pos * w4[j]); }
                else         { tq = sinf(pos * w4[j] + bias); tk = sinf(pos * w4[j]); }
                pq[j] = bf16_rne(bf16_tof(pq0[j]) * tq);
                pk[j] = bf16_rne(bf16_tof(pk0[j]) * tk);
            }
        }
        const float s4[4] = {sv.x, sv.y, sv.z, sv.w};
        #pragma unroll
        for (int j = 0; j < 4; ++j) ps[j] = bf16_rne(s4[j]);
        *(ushort4*)&qfL[r * LDA + c4] = qh;
        *(ushort4*)&kfL[r * LDA + c4] = kh;
        *(ushort4*)&SpL[r * LDA + c4] = sh;
    }
    if (t < DH)
        zl[t] = zsum[((size_t)(br * NHTOT + nh) * NCHUNK + c) * DH + t];
    __syncthreads();

    // ---- GEMM1 (scores) + GEMM2 (num from S-prefix) ----
    floatx4 acc1[2][2], acc2[2][2];
    #pragma unroll
    for (int i = 0; i < 2; ++i)
        #pragma unroll
        for (int j = 0; j < 2; ++j) {
            acc1[i][j] = (floatx4){0.f, 0.f, 0.f, 0.f};
            acc2[i][j] = (floatx4){0.f, 0.f, 0.f, 0.f};
        }
    #pragma unroll
    for (int kk = 0; kk < 2; ++kk) {
        short8 a[2], b1[2], b2[2];
        #pragma unroll
        for (int mi = 0; mi < 2; ++mi)
            a[mi] = *(const short8*)&qfL[(wm * 32 + mi * 16 + l16) * LDA + kk * 32 + quad * 8];
        #pragma unroll
        for (int ni = 0; ni < 2; ++ni) {
            b1[ni] = *(const short8*)&kfL[(wn * 32 + ni * 16 + l16) * LDA + kk * 32 + quad * 8];
            b2[ni] = *(const short8*)&SpL[(wn * 32 + ni * 16 + l16) * LDA + kk * 32 + quad * 8];
        }
        #pragma unroll
        for (int ni = 0; ni < 2; ++ni)
            #pragma unroll
            for (int mi = 0; mi < 2; ++mi) {
                acc1[mi][ni] = __builtin_amdgcn_mfma_f32_16x16x32_bf16(a[mi], b1[ni], acc1[mi][ni], 0, 0, 0);
                acc2[mi][ni] = __builtin_amdgcn_mfma_f32_16x16x32_bf16(a[mi], b2[ni], acc2[mi][ni], 0, 0, 0);
            }
    }

    // den part 1: qf . z
    {
        const int l = t & 63, seg = t >> 6;
        float s = 0.f;
        #pragma unroll
        for (int j2 = 0; j2 < 2; ++j2) {
            const short8 v8 = *(const short8*)&qfL[l * LDA + seg * 16 + j2 * 8];
            #pragma unroll
            for (int j = 0; j < 8; ++j)
                s += bf16_tof((unsigned short)v8[j]) * zl[seg * 16 + j2 * 8 + j];
        }
        dpart[seg][l] = s;
    }

    // masked scores -> [l][k] bf16
    #pragma unroll
    for (int mi = 0; mi < 2; ++mi)
        #pragma unroll
        for (int ni = 0; ni < 2; ++ni) {
            const int kcol = wn * 32 + ni * 16 + l16;
            #pragma unroll
            for (int r = 0; r < 4; ++r) {
                const int lrow = wm * 32 + mi * 16 + quad * 4 + r;
                const float v = (kcol <= lrow) ? acc1[mi][ni][r] : 0.f;
                scA[lrow * LDA + kcol] = bf16_rne(v);
            }
        }
    __syncthreads();

    // ---- GEMM3: num += scores * v ----
    #pragma unroll
    for (int kk = 0; kk < 2; ++kk) {
        short8 a[2], b[2];
        #pragma unroll
        for (int mi = 0; mi < 2; ++mi)
            a[mi] = *(const short8*)&scA[(wm * 32 + mi * 16 + l16) * LDA + kk * 32 + quad * 8];
        #pragma unroll
        for (int ni = 0; ni < 2; ++ni)
            b[ni] = *(const short8*)&vTL[(wn * 32 + ni * 16 + l16) * LDA + kk * 32 + quad * 8];
        #pragma unroll
        for (int ni = 0; ni < 2; ++ni)
            #pragma unroll
            for (int mi = 0; mi < 2; ++mi)
                acc2[mi][ni] = __builtin_amdgcn_mfma_f32_16x16x32_bf16(a[mi], b[ni], acc2[mi][ni], 0, 0, 0);
    }

    // den part 2: row sums of masked scores
    {
        const int l = t & 63, seg = t >> 6;
        float s = 0.f;
        #pragma unroll
        for (int j2 = 0; j2 < 2; ++j2) {
            const short8 v8 = *(const short8*)&scA[l * LDA + seg * 16 + j2 * 8];
            #pragma unroll
            for (int j = 0; j < 8; ++j) s += bf16_tof((unsigned short)v8[j]);
        }
        dpart[4 + seg][l] = s;
    }
    __syncthreads();

    if (t < DH) {
        const float dl = dpart[0][t] + dpart[1][t] + dpart[2][t] + dpart[3][t]
                       + dpart[4][t] + dpart[5][t] + dpart[6][t] + dpart[7][t];
        denP[((size_t)(br * NHTOT + nh)) * LSEQ + c * CHUNK + t] = dl;
    }

    #pragma unroll
    for (int mi = 0; mi < 2; ++mi)
        #pragma unroll
        for (int ni = 0; ni < 2; ++ni) {
            const int e = wn * 32 + ni * 16 + l16;
            #pragma unroll
            for (int r = 0; r < 4; ++r) {
                const int l = c * CHUNK + wm * 32 + mi * 16 + quad * 4 + r;
                numP[(((size_t)br * 2 + n) * LSEQ + l) * DIM + h * DH + e] =
                    bf16_rne(acc2[mi][ni][r]);
            }
        }
}

// ---------------------------------------------------------------------------
// Kernel D: out = (num0+num1+num2) / (den0+den1+den2).  numP is bf16.
// ---------------------------------------------------------------------------
__global__ __launch_bounds__(256) void combine_kernel(
    const unsigned short* __restrict__ numP, const float* __restrict__ denP,
    float* __restrict__ outp)
{
    const int i = blockIdx.x * 256 + threadIdx.x;   // ushort4 index, 262144
    const int row = i >> 7;
    const int ci  = i & 127;
    const int n = row >> 10, l = row & (LSEQ - 1), h = ci >> 4;
    const int nh = n * NHEAD + h;
    const ushort4* N = (const ushort4*)numP;
    const ushort4 a = N[i];
    const ushort4 b = N[i + 262144];
    const ushort4 cc = N[i + 524288];
    const float ds = denP[(size_t)nh * LSEQ + l]
                   + denP[((size_t)NHTOT + nh) * LSEQ + l]
                   + denP[((size_t)2 * NHTOT + nh) * LSEQ + l];
    const float inv = 1.f / ds;
    float4 o;
    o.x = (bf16_tof(a.x) + bf16_tof(b.x) + bf16_tof(cc.x)) * inv;
    o.y = (bf16_tof(a.y) + bf16_tof(b.y) + bf16_tof(cc.y)) * inv;
    o.z = (bf16_tof(a.z) + bf16_tof(b.z) + bf16_tof(cc.z)) * inv;
    o.w = (bf16_tof(a.w) + bf16_tof(b.w) + bf16_tof(cc.w)) * inv;
    ((float4*)outp)[i] = o;
}

extern "C" void kernel_launch(void* const* d_in, const int* in_sizes, int n_in,
                              void* d_out, int out_size, void* d_ws, size_t ws_size,
                              hipStream_t stream) {
    const float* query = (const float*)d_in[0];
    const float* key   = (const float*)d_in[1];
    const float* Wq    = (const float*)d_in[2];
    const float* Wk    = (const float*)d_in[3];
    const float* Wv    = (const float*)d_in[4];
    const float* pw    = (const float*)d_in[5];
    const float* pb    = (const float*)d_in[6];

    unsigned short* U = (unsigned short*)d_ws;
    float* F = (float*)d_ws;
    unsigned short* qbuf = U;                 // 1,048,576 u16
    unsigned short* kbuf = U + 1048576;
    unsigned short* vbuf = U + 2097152;       // ends at byte 6,291,456
    float* Ssum = F + 1572864;                // 3,145,728 f32 ([br][nh][c][e][d])
    float* zsum = F + 4718592;                // 49,152 f32
    unsigned short* numP = U + 9535488;       // 3,145,728 u16 (bf16)
    float* denP = F + 6340608;                // 49,152 f32 -> ~25.6 MB total

    proj_kernel<<<dim3(32, 8, 3), 256, 0, stream>>>(
        query, key, Wq, Wk, Wv, qbuf, kbuf, vbuf);
    chunksum_kernel<<<dim3(NCHUNK, NHTOT, 3), 256, 0, stream>>>(
        kbuf, vbuf, pw, Ssum, zsum);
    scan_kernel<<<dim3(3 * NHTOT, NCHUNK), 256, 0, stream>>>(Ssum, zsum);
    attn_kernel<<<dim3(NCHUNK, NHTOT, 3), 256, 0, stream>>>(
        qbuf, kbuf, vbuf, Ssum, zsum, pw, pb, numP, denP);
    combine_kernel<<<dim3(1024), 256, 0, stream>>>(numP, denP, (float*)d_out);
}

// Round 11
// 124.347 us; speedup vs baseline: 1.0019x; 1.0019x over previous
//
#include <hip/hip_runtime.h>
#include <hip/hip_bf16.h>

#define LSEQ   1024
#define NHEAD  8
#define DH     64
#define DIM    512
#define CHUNK  64
#define NCHUNK 16
#define NHTOT  16
#define LDB    68    // ushort LDS row stride for proj
#define LDA    72    // ushort LDS row stride for attn/chunksum (144 B, 16B-aligned)

typedef __attribute__((ext_vector_type(8))) short short8;
typedef __attribute__((ext_vector_type(4))) float floatx4;

__device__ __forceinline__ float softplusf_(float x) {
    if (x > 20.f) return x;
    return log1pf(expf(x));
}
__device__ __forceinline__ unsigned short bf16_rne(float x) {
    unsigned int u = __float_as_uint(x);
    u += 0x7FFFu + ((u >> 16) & 1u);
    return (unsigned short)(u >> 16);
}
__device__ __forceinline__ float bf16_tof(unsigned short h) {
    return __uint_as_float(((unsigned int)h) << 16);
}

// ---------------------------------------------------------------------------
// Kernel A: C = X @ W^T, single-pass bf16 MFMA.  64x64 tile, grid (32,8,3).
// ---------------------------------------------------------------------------
__global__ __launch_bounds__(256) void proj_kernel(
    const float* __restrict__ query, const float* __restrict__ key,
    const float* __restrict__ Wq, const float* __restrict__ Wk,
    const float* __restrict__ Wv,
    unsigned short* __restrict__ qbuf, unsigned short* __restrict__ kbuf,
    unsigned short* __restrict__ vbuf)
{
    const int mt  = blockIdx.x;
    const int ot  = blockIdx.y;
    const int sel = blockIdx.z;
    const int t   = threadIdx.x;

    const float* __restrict__ X = (sel == 0) ? query : key;
    const float* __restrict__ W = (sel == 0) ? Wq : (sel == 1) ? Wk : Wv;
    unsigned short* __restrict__ obuf = (sel == 0) ? qbuf : (sel == 1) ? kbuf : vbuf;

    __shared__ unsigned short As[64 * LDB];
    __shared__ unsigned short Bs[64 * LDB];

    const int m0 = mt * 64, o0 = ot * 64;
    const int lane = t & 63, wave = t >> 6;
    const int quad = lane >> 4, l16 = lane & 15;
    const int wm = wave >> 1, wn = wave & 1;

    const int srow = t >> 2;
    const int sc16 = (t & 3) * 16;

    floatx4 acc[2][2];
    #pragma unroll
    for (int i = 0; i < 2; ++i)
        #pragma unroll
        for (int j = 0; j < 2; ++j) acc[i][j] = (floatx4){0.f, 0.f, 0.f, 0.f};

    float4 ax[4], bx4[4];
    #pragma unroll
    for (int i = 0; i < 4; ++i) {
        ax[i]  = *(const float4*)&X[(size_t)(m0 + srow) * DIM + sc16 + i * 4];
        bx4[i] = *(const float4*)&W[(size_t)(o0 + srow) * DIM + sc16 + i * 4];
    }

    for (int kt = 0; kt < DIM; kt += 64) {
        __syncthreads();
        {
            short8 a0, a1, b0, b1;
            #pragma unroll
            for (int i = 0; i < 2; ++i) {
                const float va[4] = {ax[i].x, ax[i].y, ax[i].z, ax[i].w};
                const float vb[4] = {bx4[i].x, bx4[i].y, bx4[i].z, bx4[i].w};
                #pragma unroll
                for (int j = 0; j < 4; ++j) {
                    a0[i * 4 + j] = (short)bf16_rne(va[j]);
                    b0[i * 4 + j] = (short)bf16_rne(vb[j]);
                }
            }
            #pragma unroll
            for (int i = 2; i < 4; ++i) {
                const float va[4] = {ax[i].x, ax[i].y, ax[i].z, ax[i].w};
                const float vb[4] = {bx4[i].x, bx4[i].y, bx4[i].z, bx4[i].w};
                #pragma unroll
                for (int j = 0; j < 4; ++j) {
                    a1[(i - 2) * 4 + j] = (short)bf16_rne(va[j]);
                    b1[(i - 2) * 4 + j] = (short)bf16_rne(vb[j]);
                }
            }
            *(short8*)&As[srow * LDB + sc16]     = a0;
            *(short8*)&As[srow * LDB + sc16 + 8] = a1;
            *(short8*)&Bs[srow * LDB + sc16]     = b0;
            *(short8*)&Bs[srow * LDB + sc16 + 8] = b1;
        }
        __syncthreads();

        if (kt + 64 < DIM) {
            #pragma unroll
            for (int i = 0; i < 4; ++i) {
                ax[i]  = *(const float4*)&X[(size_t)(m0 + srow) * DIM + kt + 64 + sc16 + i * 4];
                bx4[i] = *(const float4*)&W[(size_t)(o0 + srow) * DIM + kt + 64 + sc16 + i * 4];
            }
        }

        #pragma unroll
        for (int s = 0; s < 2; ++s) {
            short8 af[2], bf[2];
            #pragma unroll
            for (int mi = 0; mi < 2; ++mi)
                af[mi] = *(const short8*)&As[(wm * 32 + mi * 16 + l16) * LDB + s * 32 + quad * 8];
            #pragma unroll
            for (int ni = 0; ni < 2; ++ni)
                bf[ni] = *(const short8*)&Bs[(wn * 32 + ni * 16 + l16) * LDB + s * 32 + quad * 8];
            #pragma unroll
            for (int ni = 0; ni < 2; ++ni)
                #pragma unroll
                for (int mi = 0; mi < 2; ++mi)
                    acc[mi][ni] = __builtin_amdgcn_mfma_f32_16x16x32_bf16(af[mi], bf[ni], acc[mi][ni], 0, 0, 0);
        }
    }

    const int h = ot;
    #pragma unroll
    for (int mi = 0; mi < 2; ++mi)
        #pragma unroll
        for (int ni = 0; ni < 2; ++ni) {
            const int d = wn * 32 + ni * 16 + l16;
            #pragma unroll
            for (int r = 0; r < 4; ++r) {
                const int m = m0 + wm * 32 + mi * 16 + quad * 4 + r;
                const int n = m >> 10, l = m & (LSEQ - 1);
                float val = acc[mi][ni][r];
                if (sel < 2) val = softplusf_(val);
                obuf[(((size_t)(n * NHEAD + h)) * LSEQ + l) * DH + d] = bf16_rne(val);
            }
        }
}

// ---------------------------------------------------------------------------
// Kernel B (MFMA): per-(c,nh,br) chunk sums, stored TRANSPOSED f32:
//   Ssum[br][nh][c][e][d],  zsum[...][d].
// ---------------------------------------------------------------------------
__global__ __launch_bounds__(256) void chunksum_kernel(
    const unsigned short* __restrict__ kbuf, const unsigned short* __restrict__ vbuf,
    const float* __restrict__ pw,
    float* __restrict__ Ssum, float* __restrict__ zsum)
{
    const int c  = blockIdx.x;
    const int nh = blockIdx.y;
    const int br = blockIdx.z;
    const int h  = nh & (NHEAD - 1);
    const int t  = threadIdx.x;
    const int lane = t & 63, wave = t >> 6;
    const int quad = lane >> 4, l16 = lane & 15;
    const int wm = wave >> 1, wn = wave & 1;

    __shared__ unsigned short kfT[64 * LDA];  // [d][k]
    __shared__ unsigned short vT[64 * LDA];   // [e][k]
    __shared__ float dpart[4][64];

    const size_t base = ((size_t)nh * LSEQ + (size_t)c * CHUNK) * DH;

    {
        const int col = t & 63;
        const int kq  = (t >> 6) * 16;
        const float w = pw[h * DH + col];
        unsigned short kfv[16], vvv[16];
        #pragma unroll
        for (int j = 0; j < 16; ++j) {
            const int k = kq + j;
            const unsigned short kraw = kbuf[base + (size_t)k * DH + col];
            vvv[j] = vbuf[base + (size_t)k * DH + col];
            if (br == 0) kfv[j] = kraw;
            else {
                const float pos = (float)(c * CHUNK + k);
                const float f = (br == 1) ? cosf(pos * w) : sinf(pos * w);
                kfv[j] = bf16_rne(bf16_tof(kraw) * f);
            }
        }
        #pragma unroll
        for (int g = 0; g < 4; ++g) {
            ushort4 a, b;
            a.x = kfv[g * 4]; a.y = kfv[g * 4 + 1]; a.z = kfv[g * 4 + 2]; a.w = kfv[g * 4 + 3];
            b.x = vvv[g * 4]; b.y = vvv[g * 4 + 1]; b.z = vvv[g * 4 + 2]; b.w = vvv[g * 4 + 3];
            *(ushort4*)&kfT[col * LDA + kq + g * 4] = a;
            *(ushort4*)&vT[col * LDA + kq + g * 4]  = b;
        }
    }
    __syncthreads();

    floatx4 acc[2][2];
    #pragma unroll
    for (int i = 0; i < 2; ++i)
        #pragma unroll
        for (int j = 0; j < 2; ++j) acc[i][j] = (floatx4){0.f, 0.f, 0.f, 0.f};

    #pragma unroll
    for (int kk = 0; kk < 2; ++kk) {
        short8 a[2], b[2];
        #pragma unroll
        for (int mi = 0; mi < 2; ++mi)
            a[mi] = *(const short8*)&vT[(wm * 32 + mi * 16 + l16) * LDA + kk * 32 + quad * 8];
        #pragma unroll
        for (int ni = 0; ni < 2; ++ni)
            b[ni] = *(const short8*)&kfT[(wn * 32 + ni * 16 + l16) * LDA + kk * 32 + quad * 8];
        #pragma unroll
        for (int ni = 0; ni < 2; ++ni)
            #pragma unroll
            for (int mi = 0; mi < 2; ++mi)
                acc[mi][ni] = __builtin_amdgcn_mfma_f32_16x16x32_bf16(a[mi], b[ni], acc[mi][ni], 0, 0, 0);
    }

    {
        const int d = t & 63, seg = t >> 6;
        float s = 0.f;
        #pragma unroll
        for (int j2 = 0; j2 < 2; ++j2) {
            const short8 v8 = *(const short8*)&kfT[d * LDA + seg * 16 + j2 * 8];
            #pragma unroll
            for (int j = 0; j < 8; ++j) s += bf16_tof((unsigned short)v8[j]);
        }
        dpart[seg][d] = s;
    }
    __syncthreads();
    if (t < DH) {
        zsum[((size_t)(br * NHTOT + nh) * NCHUNK + c) * DH + t] =
            dpart[0][t] + dpart[1][t] + dpart[2][t] + dpart[3][t];
    }

    float* Sg = Ssum + ((size_t)(br * NHTOT + nh) * NCHUNK + c) * (DH * DH);
    #pragma unroll
    for (int mi = 0; mi < 2; ++mi)
        #pragma unroll
        for (int ni = 0; ni < 2; ++ni) {
            const int d = wn * 32 + ni * 16 + l16;
            #pragma unroll
            for (int r = 0; r < 4; ++r) {
                const int e = wm * 32 + mi * 16 + quad * 4 + r;
                Sg[e * DH + d] = acc[mi][ni][r];
            }
        }
}

// ---------------------------------------------------------------------------
// Kernel B2: in-place exclusive prefix over chunks; grid (48, 16) = 768 blocks.
// ---------------------------------------------------------------------------
__global__ __launch_bounds__(256) void scan_kernel(
    float* __restrict__ Ssum, float* __restrict__ zsum)
{
    const int b = blockIdx.x;
    const int s = blockIdx.y;
    const int idx = s * 256 + threadIdx.x;

    float* S = Ssum + (size_t)b * NCHUNK * (DH * DH);
    float v[NCHUNK];
    #pragma unroll
    for (int c = 0; c < NCHUNK; ++c) v[c] = S[c * (DH * DH) + idx];
    float run = 0.f;
    #pragma unroll
    for (int c = 0; c < NCHUNK; ++c) {
        const float nv = v[c];
        S[c * (DH * DH) + idx] = run;
        run += nv;
    }
    if (s == 0 && threadIdx.x < DH) {
        float* z = zsum + (size_t)b * NCHUNK * DH;
        float zv[NCHUNK];
        #pragma unroll
        for (int c = 0; c < NCHUNK; ++c) zv[c] = z[c * DH + threadIdx.x];
        float zr = 0.f;
        #pragma unroll
        for (int c = 0; c < NCHUNK; ++c) {
            const float nv = zv[c];
            z[c * DH + threadIdx.x] = zr;
            zr += nv;
        }
    }
}

// ---------------------------------------------------------------------------
// Kernel C (MFMA, branch-fused): grid (c, nh, l-half) = 512 blocks.
// Per block: 32 l rows x 64 e cols.  br-loop accumulates scores / num-prefix /
// den in REGISTERS (parallel staging each iter — not R8's serialized prefix).
// One masked GEMM with v afterwards; writes final out = num/den directly.
// Eliminates numP/denP round-trip and the combine kernel.
// ---------------------------------------------------------------------------
__global__ __launch_bounds__(256) void attn_kernel(
    const unsigned short* __restrict__ qbuf, const unsigned short* __restrict__ kbuf,
    const unsigned short* __restrict__ vbuf,
    const float* __restrict__ Ssum, const float* __restrict__ zsum,
    const float* __restrict__ pw, const float* __restrict__ pb,
    float* __restrict__ outp)
{
    const int c  = blockIdx.x;
    const int nh = blockIdx.y;
    const int lh = blockIdx.z;          // 0/1: which 32-row half of the chunk
    const int n  = nh >> 3;
    const int h  = nh & (NHEAD - 1);
    const int t  = threadIdx.x;
    const int lane = t & 63, wave = t >> 6;
    const int quad = lane >> 4, l16 = lane & 15;
    const int wm = wave >> 1, wn = wave & 1;   // wave tile: 16 rows x 32 cols

    __shared__ unsigned short vTL[64 * LDA];  // [e][k]
    __shared__ unsigned short kfL[64 * LDA];  // [k][d]   (restaged per br)
    __shared__ unsigned short SpL[64 * LDA];  // [e][d]   (restaged per br)
    __shared__ unsigned short qfL[32 * LDA];  // [l][d]   (restaged per br)
    __shared__ unsigned short scA[32 * LDA];  // combined masked scores [l][k]
    __shared__ float zl[DH];
    __shared__ float dpart[8][32];
    __shared__ float dl[32];

    const size_t base = ((size_t)nh * LSEQ + (size_t)c * CHUNK) * DH;
    const float PI_ = 3.14159265358979323846f;

    // ---- stage v^T once (thread = col e, wave = k-quarter) ----
    {
        const int col = t & 63;
        const int kq  = (t >> 6) * 16;
        unsigned short vvv[16];
        #pragma unroll
        for (int j = 0; j < 16; ++j)
            vvv[j] = vbuf[base + (size_t)(kq + j) * DH + col];
        #pragma unroll
        for (int g = 0; g < 4; ++g) {
            ushort4 b;
            b.x = vvv[g * 4]; b.y = vvv[g * 4 + 1]; b.z = vvv[g * 4 + 2]; b.w = vvv[g * 4 + 3];
            *(ushort4*)&vTL[col * LDA + kq + g * 4] = b;
        }
    }

    floatx4 accS[2], accN[2];
    #pragma unroll
    for (int i = 0; i < 2; ++i) {
        accS[i] = (floatx4){0.f, 0.f, 0.f, 0.f};
        accN[i] = (floatx4){0.f, 0.f, 0.f, 0.f};
    }
    float den_reg = 0.f;   // partial: row l = t&31, segment = t>>5

    for (int br = 0; br < 3; ++br) {
        __syncthreads();   // prior iteration's readers done (also covers vTL)

        // kfL + SpL: 64x64 each, 4 ushort4/thread
        const float* Sg = Ssum + ((size_t)(br * NHTOT + nh) * NCHUNK + c) * (DH * DH);
        #pragma unroll
        for (int i = 0; i < 4; ++i) {
            const int idx = i * 256 + t;
            const int r  = idx >> 4;
            const int c4 = (idx & 15) * 4;
            const ushort4 kv = *(const ushort4*)&kbuf[base + (size_t)r * DH + c4];
            const float4  sv = *(const float4*)&Sg[r * DH + c4];
            const unsigned short* pk0 = (const unsigned short*)&kv;
            ushort4 kh, sh;
            unsigned short* pk = (unsigned short*)&kh;
            unsigned short* ps = (unsigned short*)&sh;
            if (br == 0) {
                #pragma unroll
                for (int j = 0; j < 4; ++j) pk[j] = pk0[j];
            } else {
                const float4 wv = *(const float4*)&pw[h * DH + c4];
                const float w4[4] = {wv.x, wv.y, wv.z, wv.w};
                const float pos = (float)(c * CHUNK + r);
                #pragma unroll
                for (int j = 0; j < 4; ++j) {
                    const float tk = (br == 1) ? cosf(pos * w4[j]) : sinf(pos * w4[j]);
                    pk[j] = bf16_rne(bf16_tof(pk0[j]) * tk);
                }
            }
            const float s4[4] = {sv.x, sv.y, sv.z, sv.w};
            #pragma unroll
            for (int j = 0; j < 4; ++j) ps[j] = bf16_rne(s4[j]);
            *(ushort4*)&kfL[r * LDA + c4] = kh;
            *(ushort4*)&SpL[r * LDA + c4] = sh;
        }

        // qfL: 32x64, 2 ushort4/thread (rows lh*32 .. lh*32+31)
        #pragma unroll
        for (int i = 0; i < 2; ++i) {
            const int idx = i * 256 + t;
            const int r  = idx >> 4;               // local row 0..31
            const int c4 = (idx & 15) * 4;
            const int rg = lh * 32 + r;
            const ushort4 qv = *(const ushort4*)&qbuf[base + (size_t)rg * DH + c4];
            const unsigned short* pq0 = (const unsigned short*)&qv;
            ushort4 qh;
            unsigned short* pq = (unsigned short*)&qh;
            if (br == 0) {
                #pragma unroll
                for (int j = 0; j < 4; ++j) pq[j] = pq0[j];
            } else {
                const float4 wv  = *(const float4*)&pw[h * DH + c4];
                const float4 pbv = *(const float4*)&pb[h * DH + c4];
                const float w4[4] = {wv.x, wv.y, wv.z, wv.w};
                const float b4[4] = {pbv.x, pbv.y, pbv.z, pbv.w};
                const float pos = (float)(c * CHUNK + rg);
                #pragma unroll
                for (int j = 0; j < 4; ++j) {
                    const float bias = PI_ / (1.f + expf(-b4[j]));
                    const float tq = (br == 1) ? cosf(pos * w4[j] + bias)
                                               : sinf(pos * w4[j] + bias);
                    pq[j] = bf16_rne(bf16_tof(pq0[j]) * tq);
                }
            }
            *(ushort4*)&qfL[r * LDA + c4] = qh;
        }
        if (t < DH)
            zl[t] = zsum[((size_t)(br * NHTOT + nh) * NCHUNK + c) * DH + t];
        __syncthreads();

        // GEMM: scores += qf.kf^T ; num += qf.Sp^T
        #pragma unroll
        for (int kk = 0; kk < 2; ++kk) {
            const short8 a = *(const short8*)&qfL[(wm * 16 + l16) * LDA + kk * 32 + quad * 8];
            short8 b1[2], b2[2];
            #pragma unroll
            for (int ni = 0; ni < 2; ++ni) {
                b1[ni] = *(const short8*)&kfL[(wn * 32 + ni * 16 + l16) * LDA + kk * 32 + quad * 8];
                b2[ni] = *(const short8*)&SpL[(wn * 32 + ni * 16 + l16) * LDA + kk * 32 + quad * 8];
            }
            #pragma unroll
            for (int ni = 0; ni < 2; ++ni) {
                accS[ni] = __builtin_amdgcn_mfma_f32_16x16x32_bf16(a, b1[ni], accS[ni], 0, 0, 0);
                accN[ni] = __builtin_amdgcn_mfma_f32_16x16x32_bf16(a, b2[ni], accN[ni], 0, 0, 0);
            }
        }

        // den part 1: qf . z   (row l = t&31, 8-d segment = t>>5)
        {
            const int l = t & 31, dseg = t >> 5;
            float s = 0.f;
            #pragma unroll
            for (int j = 0; j < 8; ++j) {
                const int d = dseg * 8 + j;
                s += bf16_tof(qfL[l * LDA + d]) * zl[d];
            }
            den_reg += s;
        }
    }

    // ---- combined masked scores -> scA bf16 ----
    #pragma unroll
    for (int ni = 0; ni < 2; ++ni) {
        const int kcol = wn * 32 + ni * 16 + l16;
        #pragma unroll
        for (int r = 0; r < 4; ++r) {
            const int lrow = wm * 16 + quad * 4 + r;            // local 0..31
            const float v = (kcol <= lh * 32 + lrow) ? accS[ni][r] : 0.f;
            scA[lrow * LDA + kcol] = bf16_rne(v);
        }
    }
    __syncthreads();

    // ---- GEMM: num += scores . v ----
    #pragma unroll
    for (int kk = 0; kk < 2; ++kk) {
        const short8 a = *(const short8*)&scA[(wm * 16 + l16) * LDA + kk * 32 + quad * 8];
        #pragma unroll
        for (int ni = 0; ni < 2; ++ni) {
            const short8 b = *(const short8*)&vTL[(wn * 32 + ni * 16 + l16) * LDA + kk * 32 + quad * 8];
            accN[ni] = __builtin_amdgcn_mfma_f32_16x16x32_bf16(a, b, accN[ni], 0, 0, 0);
        }
    }

    // den part 2: row sums of masked scores
    {
        const int l = t & 31, kseg = t >> 5;
        float s = 0.f;
        #pragma unroll
        for (int j = 0; j < 8; ++j)
            s += bf16_tof(scA[l * LDA + kseg * 8 + j]);
        dpart[kseg][l] = den_reg + s;
    }
    __syncthreads();
    if (t < 32) {
        float s = 0.f;
        #pragma unroll
        for (int g = 0; g < 8; ++g) s += dpart[g][t];
        dl[t] = 1.f / s;
    }
    __syncthreads();

    // ---- out = num * (1/den), direct final write ----
    #pragma unroll
    for (int ni = 0; ni < 2; ++ni) {
        const int e = wn * 32 + ni * 16 + l16;
        #pragma unroll
        for (int r = 0; r < 4; ++r) {
            const int lrow = wm * 16 + quad * 4 + r;
            const int l = c * CHUNK + lh * 32 + lrow;
            outp[((size_t)n * LSEQ + l) * DIM + h * DH + e] = accN[ni][r] * dl[lrow];
        }
    }
}

extern "C" void kernel_launch(void* const* d_in, const int* in_sizes, int n_in,
                              void* d_out, int out_size, void* d_ws, size_t ws_size,
                              hipStream_t stream) {
    const float* query = (const float*)d_in[0];
    const float* key   = (const float*)d_in[1];
    const float* Wq    = (const float*)d_in[2];
    const float* Wk    = (const float*)d_in[3];
    const float* Wv    = (const float*)d_in[4];
    const float* pw    = (const float*)d_in[5];
    const float* pb    = (const float*)d_in[6];

    unsigned short* U = (unsigned short*)d_ws;
    float* F = (float*)d_ws;
    unsigned short* qbuf = U;                 // 1,048,576 u16
    unsigned short* kbuf = U + 1048576;
    unsigned short* vbuf = U + 2097152;       // ends at byte 6,291,456
    float* Ssum = F + 1572864;                // 3,145,728 f32 ([br][nh][c][e][d])
    float* zsum = F + 4718592;                // 49,152 f32 -> ~19.1 MB total

    proj_kernel<<<dim3(32, 8, 3), 256, 0, stream>>>(
        query, key, Wq, Wk, Wv, qbuf, kbuf, vbuf);
    chunksum_kernel<<<dim3(NCHUNK, NHTOT, 3), 256, 0, stream>>>(
        kbuf, vbuf, pw, Ssum, zsum);
    scan_kernel<<<dim3(3 * NHTOT, NCHUNK), 256, 0, stream>>>(Ssum, zsum);
    attn_kernel<<<dim3(NCHUNK, NHTOT, 2), 256, 0, stream>>>(
        qbuf, kbuf, vbuf, Ssum, zsum, pw, pb, (float*)d_out);
}

// Round 12
// 118.887 us; speedup vs baseline: 1.0479x; 1.0459x over previous
//
#include <hip/hip_runtime.h>
#include <hip/hip_bf16.h>

#define LSEQ   1024
#define NHEAD  8
#define DH     64
#define DIM    512
#define NHTOT  16
#define DF     192   // concatenated feature dim: [plain, cos, sin]
#define LDB    68    // ushort LDS row stride for proj tiles
#define LDQ    200   // ushort LDS row stride for 192-wide feature tiles (400 B)
#define LDV    72    // ushort LDS row stride for 64-wide tiles (144 B)

typedef __attribute__((ext_vector_type(8))) short short8;
typedef __attribute__((ext_vector_type(4))) float floatx4;

__device__ __forceinline__ float softplusf_(float x) {
    if (x > 20.f) return x;
    return log1pf(expf(x));
}
__device__ __forceinline__ unsigned short bf16_rne(float x) {
    unsigned int u = __float_as_uint(x);
    u += 0x7FFFu + ((u >> 16) & 1u);
    return (unsigned short)(u >> 16);
}
__device__ __forceinline__ float bf16_tof(unsigned short h) {
    return __uint_as_float(((unsigned int)h) << 16);
}

// ---------------------------------------------------------------------------
// Kernel A: projections + feature map.  C = X @ W^T (bf16 MFMA, 64x64 tile).
// sel 0: q -> Q' = [softplus(q), q'*cos(l*w+bias), q'*sin(l*w+bias)]  (192-d)
// sel 1: k -> K' = [softplus(k), k'*cos(l*w),      k'*sin(l*w)]       (192-d)
// sel 2: v -> raw bf16 (64-d)
// ---------------------------------------------------------------------------
__global__ __launch_bounds__(256) void proj_kernel(
    const float* __restrict__ query, const float* __restrict__ key,
    const float* __restrict__ Wq, const float* __restrict__ Wk,
    const float* __restrict__ Wv,
    const float* __restrict__ pw, const float* __restrict__ pb,
    unsigned short* __restrict__ qf, unsigned short* __restrict__ kf,
    unsigned short* __restrict__ vbuf)
{
    const int mt  = blockIdx.x;
    const int ot  = blockIdx.y;
    const int sel = blockIdx.z;
    const int t   = threadIdx.x;

    const float* __restrict__ X = (sel == 0) ? query : key;
    const float* __restrict__ W = (sel == 0) ? Wq : (sel == 1) ? Wk : Wv;

    __shared__ unsigned short As[64 * LDB];
    __shared__ unsigned short Bs[64 * LDB];

    const int m0 = mt * 64, o0 = ot * 64;
    const int lane = t & 63, wave = t >> 6;
    const int quad = lane >> 4, l16 = lane & 15;
    const int wm = wave >> 1, wn = wave & 1;

    const int srow = t >> 2;
    const int sc16 = (t & 3) * 16;

    floatx4 acc[2][2];
    #pragma unroll
    for (int i = 0; i < 2; ++i)
        #pragma unroll
        for (int j = 0; j < 2; ++j) acc[i][j] = (floatx4){0.f, 0.f, 0.f, 0.f};

    float4 ax[4], bx4[4];
    #pragma unroll
    for (int i = 0; i < 4; ++i) {
        ax[i]  = *(const float4*)&X[(size_t)(m0 + srow) * DIM + sc16 + i * 4];
        bx4[i] = *(const float4*)&W[(size_t)(o0 + srow) * DIM + sc16 + i * 4];
    }

    for (int kt = 0; kt < DIM; kt += 64) {
        __syncthreads();
        {
            short8 a0, a1, b0, b1;
            #pragma unroll
            for (int i = 0; i < 2; ++i) {
                const float va[4] = {ax[i].x, ax[i].y, ax[i].z, ax[i].w};
                const float vb[4] = {bx4[i].x, bx4[i].y, bx4[i].z, bx4[i].w};
                #pragma unroll
                for (int j = 0; j < 4; ++j) {
                    a0[i * 4 + j] = (short)bf16_rne(va[j]);
                    b0[i * 4 + j] = (short)bf16_rne(vb[j]);
                }
            }
            #pragma unroll
            for (int i = 2; i < 4; ++i) {
                const float va[4] = {ax[i].x, ax[i].y, ax[i].z, ax[i].w};
                const float vb[4] = {bx4[i].x, bx4[i].y, bx4[i].z, bx4[i].w};
                #pragma unroll
                for (int j = 0; j < 4; ++j) {
                    a1[(i - 2) * 4 + j] = (short)bf16_rne(va[j]);
                    b1[(i - 2) * 4 + j] = (short)bf16_rne(vb[j]);
                }
            }
            *(short8*)&As[srow * LDB + sc16]     = a0;
            *(short8*)&As[srow * LDB + sc16 + 8] = a1;
            *(short8*)&Bs[srow * LDB + sc16]     = b0;
            *(short8*)&Bs[srow * LDB + sc16 + 8] = b1;
        }
        __syncthreads();

        if (kt + 64 < DIM) {
            #pragma unroll
            for (int i = 0; i < 4; ++i) {
                ax[i]  = *(const float4*)&X[(size_t)(m0 + srow) * DIM + kt + 64 + sc16 + i * 4];
                bx4[i] = *(const float4*)&W[(size_t)(o0 + srow) * DIM + kt + 64 + sc16 + i * 4];
            }
        }

        #pragma unroll
        for (int s = 0; s < 2; ++s) {
            short8 af[2], bf[2];
            #pragma unroll
            for (int mi = 0; mi < 2; ++mi)
                af[mi] = *(const short8*)&As[(wm * 32 + mi * 16 + l16) * LDB + s * 32 + quad * 8];
            #pragma unroll
            for (int ni = 0; ni < 2; ++ni)
                bf[ni] = *(const short8*)&Bs[(wn * 32 + ni * 16 + l16) * LDB + s * 32 + quad * 8];
            #pragma unroll
            for (int ni = 0; ni < 2; ++ni)
                #pragma unroll
                for (int mi = 0; mi < 2; ++mi)
                    acc[mi][ni] = __builtin_amdgcn_mfma_f32_16x16x32_bf16(af[mi], bf[ni], acc[mi][ni], 0, 0, 0);
        }
    }

    const int h = ot;   // o0 = h*64
    const float PI_ = 3.14159265358979323846f;
    if (sel == 2) {
        #pragma unroll
        for (int mi = 0; mi < 2; ++mi)
            #pragma unroll
            for (int ni = 0; ni < 2; ++ni) {
                const int d = wn * 32 + ni * 16 + l16;
                #pragma unroll
                for (int r = 0; r < 4; ++r) {
                    const int m = m0 + wm * 32 + mi * 16 + quad * 4 + r;
                    const int n = m >> 10, l = m & (LSEQ - 1);
                    vbuf[(((size_t)(n * NHEAD + h)) * LSEQ + l) * DH + d] =
                        bf16_rne(acc[mi][ni][r]);
                }
            }
    } else {
        unsigned short* __restrict__ obuf = (sel == 0) ? qf : kf;
        #pragma unroll
        for (int ni = 0; ni < 2; ++ni) {
            const int d = wn * 32 + ni * 16 + l16;
            const float w = pw[h * DH + d];
            const float bias = (sel == 0) ? PI_ / (1.f + expf(-pb[h * DH + d])) : 0.f;
            #pragma unroll
            for (int mi = 0; mi < 2; ++mi)
                #pragma unroll
                for (int r = 0; r < 4; ++r) {
                    const int m = m0 + wm * 32 + mi * 16 + quad * 4 + r;
                    const int n = m >> 10, l = m & (LSEQ - 1);
                    const float val = softplusf_(acc[mi][ni][r]);
                    float sn, cs;
                    sincosf((float)l * w + bias, &sn, &cs);
                    const size_t ob = (((size_t)(n * NHEAD + h)) * LSEQ + l) * DF + d;
                    obuf[ob]            = bf16_rne(val);
                    obuf[ob + DH]       = bf16_rne(val * cs);
                    obuf[ob + 2 * DH]   = bf16_rne(val * sn);
                }
        }
    }
}

// ---------------------------------------------------------------------------
// Kernel B (flash-style quadratic attention over 192-d features):
//   S = tril(Q' K'^T);  out = (S V) / rowsum(S)
// Grid (p, nh, z) = (16,16,2), 512 blocks = 2/CU.  z=0: lt=p (light, <=8
// k-tiles); z=1: lt=31-p (heavy) — per-CU pairing balances (~17 iters/CU).
// Block: 32 q-rows x full 64-d out, looping 64-col k-tiles up to the diagonal.
// ---------------------------------------------------------------------------
__global__ __launch_bounds__(256) void attn_kernel(
    const unsigned short* __restrict__ qf, const unsigned short* __restrict__ kf,
    const unsigned short* __restrict__ vbuf,
    float* __restrict__ outp)
{
    const int p  = blockIdx.x;
    const int nh = blockIdx.y;
    const int z  = blockIdx.z;
    const int lt = z ? (31 - p) : p;       // 32-row l-tile index
    const int n  = nh >> 3;
    const int h  = nh & (NHEAD - 1);
    const int t  = threadIdx.x;
    const int lane = t & 63, wave = t >> 6;
    const int quad = lane >> 4, l16 = lane & 15;
    const int wm = wave >> 1, wn = wave & 1;   // wave tile: 16 rows x 32 cols

    __shared__ unsigned short qL[32 * LDQ];   // Q' tile [32][192]
    __shared__ unsigned short kL[64 * LDQ];   // K' tile [64][192]
    __shared__ unsigned short vT[64 * LDV];   // V^T tile [e][k]
    __shared__ unsigned short scA[32 * LDV];  // masked scores bf16 [l][k]
    __shared__ float denL[2][32];
    __shared__ float inv32[32];

    const size_t fbase = (size_t)nh * LSEQ;
    const int nkt = (lt >> 1) + 1;
    const int diag_kt = lt >> 1;

    // stage Q' (32x192): 6 ushort4 per thread
    #pragma unroll
    for (int i = 0; i < 6; ++i) {
        const int idx = i * 256 + t;
        const int r = idx / 48, c4 = (idx % 48) * 4;
        *(ushort4*)&qL[r * LDQ + c4] =
            *(const ushort4*)&qf[(fbase + lt * 32 + r) * DF + c4];
    }

    floatx4 accN[2];
    accN[0] = (floatx4){0.f, 0.f, 0.f, 0.f};
    accN[1] = (floatx4){0.f, 0.f, 0.f, 0.f};
    float den4[4] = {0.f, 0.f, 0.f, 0.f};

    for (int kt = 0; kt < nkt; ++kt) {
        // stage K' (64x192): 12 ushort4 per thread
        #pragma unroll
        for (int i = 0; i < 12; ++i) {
            const int idx = i * 256 + t;
            const int r = idx / 48, c4 = (idx % 48) * 4;
            *(ushort4*)&kL[r * LDQ + c4] =
                *(const ushort4*)&kf[(fbase + kt * 64 + r) * DF + c4];
        }
        // stage V^T (thread = col e, wave = k-quarter)
        {
            const int col = t & 63, kq = (t >> 6) * 16;
            unsigned short vvv[16];
            #pragma unroll
            for (int j = 0; j < 16; ++j)
                vvv[j] = vbuf[(fbase + kt * 64 + kq + j) * DH + col];
            #pragma unroll
            for (int g = 0; g < 4; ++g) {
                ushort4 b;
                b.x = vvv[g * 4]; b.y = vvv[g * 4 + 1];
                b.z = vvv[g * 4 + 2]; b.w = vvv[g * 4 + 3];
                *(ushort4*)&vT[col * LDV + kq + g * 4] = b;
            }
        }
        __syncthreads();

        // GEMM1: scores(32x64) = Q'(32x192) . K'^T, K=192 in 6 steps
        floatx4 accS[2];
        accS[0] = (floatx4){0.f, 0.f, 0.f, 0.f};
        accS[1] = (floatx4){0.f, 0.f, 0.f, 0.f};
        #pragma unroll
        for (int kk = 0; kk < 6; ++kk) {
            const short8 a = *(const short8*)&qL[(wm * 16 + l16) * LDQ + kk * 32 + quad * 8];
            #pragma unroll
            for (int ni = 0; ni < 2; ++ni) {
                const short8 b = *(const short8*)&kL[(wn * 32 + ni * 16 + l16) * LDQ + kk * 32 + quad * 8];
                accS[ni] = __builtin_amdgcn_mfma_f32_16x16x32_bf16(a, b, accS[ni], 0, 0, 0);
            }
        }

        // mask (diagonal tile only), accumulate den (f32), write scA bf16
        const bool diag = (kt == diag_kt);
        #pragma unroll
        for (int ni = 0; ni < 2; ++ni) {
            const int kcolL = wn * 32 + ni * 16 + l16;
            const int kcolG = kt * 64 + kcolL;
            #pragma unroll
            for (int r = 0; r < 4; ++r) {
                const int lrowL = wm * 16 + quad * 4 + r;
                float sval = accS[ni][r];
                if (diag && kcolG > lt * 32 + lrowL) sval = 0.f;
                den4[r] += sval;
                scA[lrowL * LDV + kcolL] = bf16_rne(sval);
            }
        }
        __syncthreads();

        // GEMM2: num += scA(32x64) . V(64x64), K=64 in 2 steps
        #pragma unroll
        for (int kk = 0; kk < 2; ++kk) {
            const short8 a = *(const short8*)&scA[(wm * 16 + l16) * LDV + kk * 32 + quad * 8];
            #pragma unroll
            for (int ni = 0; ni < 2; ++ni) {
                const short8 b = *(const short8*)&vT[(wn * 32 + ni * 16 + l16) * LDV + kk * 32 + quad * 8];
                accN[ni] = __builtin_amdgcn_mfma_f32_16x16x32_bf16(a, b, accN[ni], 0, 0, 0);
            }
        }
        __syncthreads();   // kL/vT/scA safe to overwrite next iter
    }

    // den: reduce den4 over the 16 l16-lanes of each quadrant, then across wn
    #pragma unroll
    for (int r = 0; r < 4; ++r) {
        float s = den4[r];
        s += __shfl_xor(s, 1);
        s += __shfl_xor(s, 2);
        s += __shfl_xor(s, 4);
        s += __shfl_xor(s, 8);
        if (l16 == 0) denL[wn][wm * 16 + quad * 4 + r] = s;
    }
    __syncthreads();
    if (t < 32) inv32[t] = 1.f / (denL[0][t] + denL[1][t]);
    __syncthreads();

    // out = num * (1/den)
    #pragma unroll
    for (int ni = 0; ni < 2; ++ni) {
        const int e = wn * 32 + ni * 16 + l16;
        #pragma unroll
        for (int r = 0; r < 4; ++r) {
            const int row = wm * 16 + quad * 4 + r;
            outp[((size_t)n * LSEQ + lt * 32 + row) * DIM + h * DH + e] =
                accN[ni][r] * inv32[row];
        }
    }
}

extern "C" void kernel_launch(void* const* d_in, const int* in_sizes, int n_in,
                              void* d_out, int out_size, void* d_ws, size_t ws_size,
                              hipStream_t stream) {
    const float* query = (const float*)d_in[0];
    const float* key   = (const float*)d_in[1];
    const float* Wq    = (const float*)d_in[2];
    const float* Wk    = (const float*)d_in[3];
    const float* Wv    = (const float*)d_in[4];
    const float* pw    = (const float*)d_in[5];
    const float* pb    = (const float*)d_in[6];

    unsigned short* U = (unsigned short*)d_ws;
    unsigned short* qf   = U;                 // 16*1024*192 = 3,145,728 u16
    unsigned short* kf   = U + 3145728;       // 3,145,728 u16
    unsigned short* vbuf = U + 6291456;       // 1,048,576 u16 -> 14.7 MB total

    proj_kernel<<<dim3(32, 8, 3), 256, 0, stream>>>(
        query, key, Wq, Wk, Wv, pw, pb, qf, kf, vbuf);
    attn_kernel<<<dim3(16, 16, 2), 256, 0, stream>>>(
        qf, kf, vbuf, (float*)d_out);
}